// Round 3
// baseline (583.424 us; speedup 1.0000x reference)
//
#include <hip/hip_runtime.h>

typedef unsigned short ushort_t;
typedef __attribute__((ext_vector_type(8))) __bf16 bf16x8;
typedef __attribute__((ext_vector_type(16))) float f32x16;

#define SEQ 8192
#define DIN 1024
#define DOUT 1024

// epilogue output modes
#define OM_BF16 0
#define OM_EXP  2   // bf16 exp2(scale*acc) store + per-block partial row-sums -> rsp
#define OM_NORM 3   // f32 store of acc * invrs[row]

__device__ __forceinline__ ushort_t f2bf(float f) {
  union { float f; unsigned u; } c; c.f = f;
  unsigned u = c.u;
  return (ushort_t)((u + 0x7fffu + ((u >> 16) & 1u)) >> 16);  // RNE
}

__device__ __forceinline__ void async16(ushort_t* lds, const ushort_t* g) {
  __builtin_amdgcn_global_load_lds(
      (__attribute__((address_space(1))) void*)g,
      (__attribute__((address_space(3))) void*)lds, 16, 0, 0);
}

template <int N>
__device__ __forceinline__ void waitv() {
  // counted vmcnt wait; "memory" clobber pins gload_lds / ds_read ordering
  asm volatile("s_waitcnt vmcnt(%0)" :: "n"(N) : "memory");
}

// ------- fused fp32 -> bf16 convert for x, Wq, Wk, Wv -------
__global__ __launch_bounds__(256) void cvt_all_kernel(
    const float* __restrict__ x, const float* __restrict__ wq,
    const float* __restrict__ wk, const float* __restrict__ wv,
    ushort_t* __restrict__ xb, ushort_t* __restrict__ wqkb,
    ushort_t* __restrict__ wvb) {
  int b = blockIdx.x;
  const float* src;
  ushort_t* dst;
  int idx;
  if (b < 8192) {
    src = x; dst = xb; idx = b * 256 + threadIdx.x;
  } else {
    int r = b - 8192;
    int w = r >> 10;
    idx = (r & 1023) * 256 + threadIdx.x;
    if (w == 0)      { src = wq; dst = wqkb; }
    else if (w == 1) { src = wk; dst = wqkb + DOUT * DIN; }
    else             { src = wv; dst = wvb; }
  }
  float4 f = ((const float4*)src)[idx];
  ushort4 o;
  o.x = f2bf(f.x); o.y = f2bf(f.y); o.z = f2bf(f.z); o.w = f2bf(f.w);
  ((ushort4*)dst)[idx] = o;
}

// ------- rowsum partials [32][SEQ] -> invrs[SEQ] = 1/sum -------
__global__ __launch_bounds__(256) void rowsum_inv_kernel(const float* __restrict__ rsp,
                                                         float* __restrict__ invrs) {
  int r = blockIdx.x * 256 + threadIdx.x;
  float s = 0.f;
  #pragma unroll
  for (int p2 = 0; p2 < 32; ++p2) s += rsp[p2 * SEQ + r];
  invrs[r] = 1.0f / s;
}

// ---------------- GEMM: C[M][N] = A[M][K] @ B[N][K]^T ----------------
// Round-3 restructure driven by the sum-model calibration (MfmaUtil ==
// MFMA_cyc / (MFMA + LDS-read + LDS-write) under barrier convoy):
//   - 4 waves (256 thr), wave grid 2Mx2N, wave tile (BM/2)x(BN/2) -> LDS
//     bytes/MFMA-cyc cut ~2x vs the 8-wave 2Mx4N layout.
//   - mfma_f32_32x32x16_bf16 (2495 TF ubench vs 2075 for 16x16x32): 20% fewer
//     MFMA-pipe cycles for the same FLOPs.
//   - K-tile 64, ring-2 LDS double-buffer, counted vmcnt (<LPG>, never 0 in
//     steady state), 2 raw s_barriers per K-tile. No hand lgkm waits: plain
//     pointer ds_reads + MFMA let the compiler emit fine-grained lgkmcnt and
//     hoist next-ks reads over the current MFMA cluster (m97-verified).
//   - LDS swizzle: 16B-chunk slot ^= (row&7) (8 chunks/row), applied on the
//     GLOBAL source address (gload_lds dest stays lane-linear) and on the
//     ds_read address. Conflict-free for both the 32-lane frag reads and the
//     lane-linear writes.
// Ring safety: group kt+1 (issued at top of iter kt) overwrites the slot last
// read at iter kt-1; every ds_read is register-consumed (compiler lgkm) before
// the end-of-iter barrier, and the issue sits after that barrier.
// Frag layout 32x32x16: A/B lane l -> row/col=l&31, k=(l>>5)*8+e (16B contig);
// C/D col=lane&31, row=(reg&3)+8*(reg>>2)+4*(lane>>5)  [m74/m101].
template <int OUTMODE, int SUPER, int BM, int BN>
__global__ __launch_bounds__(256, 1) void gemm4w(
    const ushort_t* __restrict__ A, const ushort_t* __restrict__ B,
    void* __restrict__ C, int lda, int ldb, int ldc, int K, float scale,
    float* __restrict__ rsp, const float* __restrict__ invrs) {
  constexpr int WM = BM / 2, WN = BN / 2;
  constexpr int MI = WM / 32, NI = WN / 32;
  constexpr int AST = BM * 64;          // elems per A stage
  constexpr int BST = BN * 64;
  constexpr int NA = BM / 32;           // gload_lds per thread per stage (A)
  constexpr int NB = BN / 32;
  constexpr int LPG = NA + NB;
  __shared__ ushort_t As[2 * AST];      // 64 KB (BM=256) / 32 KB (128)
  __shared__ ushort_t Bs[2 * BST];

  const int t = threadIdx.x;
  const int lane = t & 63;
  const int wave = t >> 6;
  const int wrM = wave >> 1, wcN = wave & 1;
  const int hi = lane >> 5, l5 = lane & 31;

  const int gx = gridDim.x;
  const int nwg = gx * gridDim.y;
  const int bid = blockIdx.y * gx + blockIdx.x;
  int mt, nt;
  if (SUPER == 1) {
    // 32x32 grid only: XCD (x>>2, x&3) owns 16mt x 8nt, walked in 4x8 chunks
    int x = bid & 7, l = bid >> 3;
    mt = ((x >> 2) << 4) + ((l >> 5) << 2) + ((l >> 3) & 3);
    nt = ((x & 3) << 3) + (l & 7);
  } else {
    // bijective chunked XCD swizzle (nwg is a multiple of 8)
    const int q8 = nwg >> 3;
    const int b2 = (bid & 7) * q8 + (bid >> 3);
    mt = b2 / gx;
    nt = b2 - mt * gx;
  }
  const int rowBase = mt * BM;
  const int colBase = nt * BN;

  // per-thread 32-bit staging source offsets (elements), bumped 64 per K-tile
  unsigned offA[NA], offB[NB];
  #pragma unroll
  for (int i = 0; i < NA; ++i) {
    int c = t + i * 256, row = c >> 3, sl = c & 7;
    offA[i] = (unsigned)((rowBase + row) * lda + ((sl ^ (row & 7)) << 3));
  }
  #pragma unroll
  for (int i = 0; i < NB; ++i) {
    int c = t + i * 256, row = c >> 3, sl = c & 7;
    offB[i] = (unsigned)((colBase + row) * ldb + ((sl ^ (row & 7)) << 3));
  }

  f32x16 acc[MI][NI] = {};

  const int NT = K / 64;

  // prologue: group 0 -> slot 0
  #pragma unroll
  for (int i = 0; i < NA; ++i) {
    async16(&As[(t + i * 256) * 8], A + offA[i]); offA[i] += 64;
  }
  #pragma unroll
  for (int i = 0; i < NB; ++i) {
    async16(&Bs[(t + i * 256) * 8], B + offB[i]); offB[i] += 64;
  }

  for (int kt = 0; kt < NT; ++kt) {
    const int cur = kt & 1;
    if (kt + 1 < NT) {
      const int nx = cur ^ 1;
      #pragma unroll
      for (int i = 0; i < NA; ++i) {
        async16(&As[nx * AST + (t + i * 256) * 8], A + offA[i]); offA[i] += 64;
      }
      #pragma unroll
      for (int i = 0; i < NB; ++i) {
        async16(&Bs[nx * BST + (t + i * 256) * 8], B + offB[i]); offB[i] += 64;
      }
      waitv<LPG>();        // group kt landed; group kt+1 stays in flight
    } else {
      waitv<0>();
    }
    __builtin_amdgcn_s_barrier();
    asm volatile("" ::: "memory");     // no ds_read hoists above barrier

    const ushort_t* as = As + cur * AST;
    const ushort_t* bs = Bs + cur * BST;
    #pragma unroll
    for (int ks = 0; ks < 4; ++ks) {
      bf16x8 a_[MI], b_[NI];
      #pragma unroll
      for (int mi = 0; mi < MI; ++mi) {
        int row = wrM * WM + mi * 32 + l5;
        int sl = (ks * 2 + hi) ^ (row & 7);
        a_[mi] = *(const bf16x8*)&as[(row * 8 + sl) * 8];
      }
      #pragma unroll
      for (int ni = 0; ni < NI; ++ni) {
        int row = wcN * WN + ni * 32 + l5;
        int sl = (ks * 2 + hi) ^ (row & 7);
        b_[ni] = *(const bf16x8*)&bs[(row * 8 + sl) * 8];
      }
      __builtin_amdgcn_s_setprio(1);
      #pragma unroll
      for (int mi = 0; mi < MI; ++mi)
        #pragma unroll
        for (int ni = 0; ni < NI; ++ni)
          acc[mi][ni] = __builtin_amdgcn_mfma_f32_32x32x16_bf16(
              a_[mi], b_[ni], acc[mi][ni], 0, 0, 0);
      __builtin_amdgcn_s_setprio(0);
    }
    __builtin_amdgcn_s_barrier();      // all waves done reading slot cur
    asm volatile("" ::: "memory");
  }

  // ---- epilogue: C/D col=lane&31, row=(reg&3)+8*(reg>>2)+4*hi ----
  float iv_[MI][16];
  if constexpr (OUTMODE == OM_NORM) {
    #pragma unroll
    for (int mi = 0; mi < MI; ++mi)
      #pragma unroll
      for (int g = 0; g < 16; ++g) {
        int rr = (g & 3) + 8 * (g >> 2) + 4 * hi;
        iv_[mi][g] = invrs[rowBase + wrM * WM + mi * 32 + rr];
      }
  }

  float* lds_rs = (float*)As;   // EXP: [2][256] partials; As dead after loop

  #pragma unroll
  for (int mi = 0; mi < MI; ++mi)
    #pragma unroll
    for (int g = 0; g < 16; ++g) {
      int rr = (g & 3) + 8 * (g >> 2) + 4 * hi;
      int grow = rowBase + wrM * WM + mi * 32 + rr;
      float s = 0.f;
      #pragma unroll
      for (int ni = 0; ni < NI; ++ni) {
        int gcol = colBase + wcN * WN + ni * 32 + l5;
        float a = acc[mi][ni][g];
        if constexpr (OUTMODE == OM_BF16) {
          ((ushort_t*)C)[(size_t)grow * ldc + gcol] = f2bf(a * scale);
        } else if constexpr (OUTMODE == OM_EXP) {
          float e = exp2f(a * scale);   // scale carries the log2(e) factor
          s += e;
          ((ushort_t*)C)[(size_t)grow * ldc + gcol] = f2bf(e);
        } else {  // OM_NORM
          ((float*)C)[(size_t)grow * ldc + gcol] = a * iv_[mi][g];
        }
      }
      if constexpr (OUTMODE == OM_EXP) {
        // reduce over the 32 lanes of this half-wave (cols of this ni-range)
        s += __shfl_xor(s, 1, 64);
        s += __shfl_xor(s, 2, 64);
        s += __shfl_xor(s, 4, 64);
        s += __shfl_xor(s, 8, 64);
        s += __shfl_xor(s, 16, 64);
        if (l5 == 0)
          lds_rs[wcN * 256 + wrM * 128 + mi * 32 + rr] = s;
      }
    }

  if constexpr (OUTMODE == OM_EXP) {
    __syncthreads();
    rsp[(size_t)nt * SEQ + rowBase + t] = lds_rs[t] + lds_rs[256 + t];
  }
}

extern "C" void kernel_launch(void* const* d_in, const int* in_sizes, int n_in,
                              void* d_out, int out_size, void* d_ws, size_t ws_size,
                              hipStream_t stream) {
  const float* x  = (const float*)d_in[0];
  const float* Wq = (const float*)d_in[1];
  const float* Wk = (const float*)d_in[2];
  const float* Wv = (const float*)d_in[3];
  float* out = (float*)d_out;

  char* p = (char*)d_ws;
  ushort_t* xb   = (ushort_t*)p; p += (size_t)SEQ * DIN * 2;        // 16 MB
  ushort_t* wqkb = (ushort_t*)p; p += (size_t)2 * DOUT * DIN * 2;   //  4 MB (Wq|Wk)
  ushort_t* wvb  = (ushort_t*)p; p += (size_t)DOUT * DIN * 2;       //  2 MB
  ushort_t* qkb  = (ushort_t*)p; p += (size_t)SEQ * 2 * DOUT * 2;   // 32 MB ([S][2048], q|k)
  ushort_t* vtb  = (ushort_t*)p; p += (size_t)DOUT * SEQ * 2;       // 16 MB (v^T)
  float*    rsp  = (float*)p;    p += (size_t)64 * SEQ * 4;         //  2 MB partial rowsums
  float*    irs  = (float*)p;    p += (size_t)SEQ * 4;              // 32 KB 1/rowsum
  ushort_t* Sb   = (ushort_t*)p; p += (size_t)SEQ * SEQ * 2;        // 128 MB

  // fp32 -> bf16 for all four tensors (one launch)
  cvt_all_kernel<<<8192 + 3 * 1024, 256, 0, stream>>>(x, Wq, Wk, Wv, xb, wqkb, wvb);

  dim3 blk(256);
  // [q|k] = x @ [Wq|Wk]^T : M=8192, N=2048, K=1024 -> 8x32 = 256 blocks (1/CU)
  gemm4w<OM_BF16, 0, 256, 256><<<dim3(2048 / 256, SEQ / 256), blk, 0, stream>>>(
      xb, wqkb, qkb, DIN, DIN, 2 * DOUT, DIN, 1.0f, nullptr, nullptr);

  // v^T = Wv @ x^T : M=1024, N=8192, K=1024 -> BM=128: 32x8 = 256 blocks
  gemm4w<OM_BF16, 0, 128, 256><<<dim3(SEQ / 256, DOUT / 128), blk, 0, stream>>>(
      wvb, xb, vtb, DIN, DIN, SEQ, DIN, 1.0f, nullptr, nullptr);

  // E = exp((q @ k^T)/32) via exp2, partial row sums -> rsp : 32x32 = 1024 blocks
  gemm4w<OM_EXP, 1, 256, 256><<<dim3(SEQ / 256, SEQ / 256), blk, 0, stream>>>(
      qkb, qkb + DOUT, Sb, 2 * DOUT, 2 * DOUT, SEQ, DIN,
      0.03125f * 1.44269504f, rsp, nullptr);

  // invrs[r] = 1 / sum_p rsp[p][r]  (32 partial tiles)
  rowsum_inv_kernel<<<SEQ / 256, 256, 0, stream>>>(rsp, irs);

  // out = (E @ v) * invrs : M=8192, N=1024, K=8192 -> BN=128: 8x32 = 256 blocks
  gemm4w<OM_NORM, 0, 256, 128><<<dim3(DOUT / 128, SEQ / 256), blk, 0, stream>>>(
      Sb, vtb, out, SEQ, SEQ, DOUT, SEQ, 1.0f, nullptr, irs);
}

// Round 4
// 474.774 us; speedup vs baseline: 1.2288x; 1.2288x over previous
//
#include <hip/hip_runtime.h>

typedef unsigned short ushort_t;
typedef __attribute__((ext_vector_type(8))) __bf16 bf16x8;
typedef __attribute__((ext_vector_type(4))) float f32x4;

#define SEQ 8192
#define DIN 1024
#define DOUT 1024

// epilogue output modes
#define OM_BF16 0
#define OM_EXP  2   // bf16 exp2(scale*acc) store + per-block partial row-sums -> rsp
#define OM_NORM 3   // f32 store of acc * invrs[row]

__device__ __forceinline__ ushort_t f2bf(float f) {
  union { float f; unsigned u; } c; c.f = f;
  unsigned u = c.u;
  return (ushort_t)((u + 0x7fffu + ((u >> 16) & 1u)) >> 16);  // RNE
}

__device__ __forceinline__ void async16(ushort_t* lds, const ushort_t* g) {
  __builtin_amdgcn_global_load_lds(
      (__attribute__((address_space(1))) void*)g,
      (__attribute__((address_space(3))) void*)lds, 16, 0, 0);
}

template <int N>
__device__ __forceinline__ void waitv() {
  asm volatile("s_waitcnt vmcnt(%0)" :: "n"(N) : "memory");
}

// ------- fused fp32 -> bf16 convert for x, Wq, Wk, Wv -------
__global__ __launch_bounds__(256) void cvt_all_kernel(
    const float* __restrict__ x, const float* __restrict__ wq,
    const float* __restrict__ wk, const float* __restrict__ wv,
    ushort_t* __restrict__ xb, ushort_t* __restrict__ wqkb,
    ushort_t* __restrict__ wvb) {
  int b = blockIdx.x;
  const float* src;
  ushort_t* dst;
  int idx;
  if (b < 8192) {
    src = x; dst = xb; idx = b * 256 + threadIdx.x;
  } else {
    int r = b - 8192;
    int w = r >> 10;
    idx = (r & 1023) * 256 + threadIdx.x;
    if (w == 0)      { src = wq; dst = wqkb; }
    else if (w == 1) { src = wk; dst = wqkb + DOUT * DIN; }
    else             { src = wv; dst = wvb; }
  }
  float4 f = ((const float4*)src)[idx];
  ushort4 o;
  o.x = f2bf(f.x); o.y = f2bf(f.y); o.z = f2bf(f.z); o.w = f2bf(f.w);
  ((ushort4*)dst)[idx] = o;
}

// ------- rowsum partials [32][SEQ] -> invrs[SEQ] = 1/sum -------
__global__ __launch_bounds__(256) void rowsum_inv_kernel(const float* __restrict__ rsp,
                                                         float* __restrict__ invrs) {
  int r = blockIdx.x * 256 + threadIdx.x;
  float s = 0.f;
  #pragma unroll
  for (int p2 = 0; p2 < 32; ++p2) s += rsp[p2 * SEQ + r];
  invrs[r] = 1.0f / s;
}

// ---------------- GEMM: C[M][N] = A[M][K] @ B[N][K]^T ----------------
// Round-4: faithful port of the verified m201 8-phase 256^2 template.
// BMxBN tile, BK=64, 512 thr = 8 waves (2M x 4N), wave tile (BM/2)x(BN/4),
// mfma_f32_16x16x32_bf16, acc[MI][NIfr] f32x4.
// LDS: 2 buffers x (A[BM][64] + B[BN][64]) bf16, each split in 2 staging
// halves; chunk-swizzle sl = c ^ (row&7) on both global source & ds_read.
// Iteration = 2 K-tiles (E=buf0, O=buf1), 8 phases; each phase:
//   {ds_read frags, stage 1 half-tile, sched_barrier, s_barrier,
//    lgkmcnt(0)+sched_barrier, setprio(1) MFMA setprio(0), s_barrier}.
// Reads per tile: P1 A-lo/ks0 + B/ks0, P2 B/ks1 + A-hi/ks0, P3 A-lo/ks1,
// P4 A-hi/ks1 (A regions last read P4, B last read P2).
// Stage plan (1 half/phase; overwrite-issue strictly after last-read phase):
//   P1: O.Ah0   P2: O.Ah1   P3: E2.Bh0  P4: E2.Bh1   (E2 = next iter's E)
//   P5: E2.Ah0  P6: E2.Ah1  P7: O2.Bh0  P8: O2.Bh1
// Counted vmcnt(2*LB) at END of P4 and P8 (before closing barrier): leaves
// exactly the 2 newest B-halves in flight; every half needed by the next
// 4 phases is then block-wide landed (per-wave drain + barrier). Never 0 in
// steady state. Prologue stages E.Bh0,E.Bh1,E.Ah0,E.Ah1,O.Bh0,O.Bh1 then
// vmcnt(2*LB). Tail: last iter suppresses P3-P8 stages, vmcnt(0) at P4.
template <int OUTMODE, int SUPER, int BM, int BN>
__global__ __launch_bounds__(512, 2) void gemm8p(
    const ushort_t* __restrict__ A, const ushort_t* __restrict__ B,
    void* __restrict__ C, int lda, int ldb, int ldc, int K, float scale,
    float* __restrict__ rsp, const float* __restrict__ invrs) {
  constexpr int WM = BM / 2, WN = BN / 4;
  constexpr int MI = BM / 32, NIfr = BN / 64;
  constexpr int MH = MI / 2;
  constexpr int AST = BM * 64, BST = BN * 64;
  constexpr int AHALF = AST / 2, BHALF = BST / 2;
  constexpr int LA = BM / 128, LB = BN / 128;   // loads/thread per half
  __shared__ ushort_t As[2 * AST];
  __shared__ ushort_t Bs[2 * BST];

  const int t = threadIdx.x;
  const int lane = t & 63;
  const int wave = t >> 6;
  const int wr = wave >> 2, wc = wave & 3;
  const int quad = lane >> 4, r16 = lane & 15;

  const int gx = gridDim.x;
  const int nwg = gx * gridDim.y;
  const int bid = blockIdx.y * gx + blockIdx.x;
  int mt, nt;
  if (SUPER == 1) {
    // 32x32 grid only: XCD (x>>2, x&3) owns 16mt x 8nt, walked in 4x8 chunks
    int x = bid & 7, l = bid >> 3;
    mt = ((x >> 2) << 4) + ((l >> 5) << 2) + ((l >> 3) & 3);
    nt = ((x & 3) << 3) + (l & 7);
  } else {
    const int q8 = nwg >> 3;
    const int b2 = (bid & 7) * q8 + (bid >> 3);
    mt = b2 / gx;
    nt = b2 - mt * gx;
  }
  const int rowBase = mt * BM;
  const int colBase = nt * BN;

  // staging offsets (elements), one set per {operand, half}; +64 per use
  unsigned offA[2][LA], offB[2][LB];
  #pragma unroll
  for (int h = 0; h < 2; ++h) {
    #pragma unroll
    for (int i = 0; i < LA; ++i) {
      int c = t + i * 512, row = c >> 3, sl = c & 7;
      offA[h][i] = (unsigned)((rowBase + h * (BM / 2) + row) * lda +
                              ((sl ^ (row & 7)) << 3));
    }
    #pragma unroll
    for (int i = 0; i < LB; ++i) {
      int c = t + i * 512, row = c >> 3, sl = c & 7;
      offB[h][i] = (unsigned)((colBase + h * (BN / 2) + row) * ldb +
                              ((sl ^ (row & 7)) << 3));
    }
  }

  auto stageA = [&](int buf, int h) {
    #pragma unroll
    for (int i = 0; i < LA; ++i) {
      async16(&As[buf * AST + h * AHALF + (t + i * 512) * 8], A + offA[h][i]);
      offA[h][i] += 64;
    }
  };
  auto stageB = [&](int buf, int h) {
    #pragma unroll
    for (int i = 0; i < LB; ++i) {
      async16(&Bs[buf * BST + h * BHALF + (t + i * 512) * 8], B + offB[h][i]);
      offB[h][i] += 64;
    }
  };

  f32x4 acc[MI][NIfr] = {};
  bf16x8 af[MH], b0[NIfr], b1[NIfr];

  auto readA = [&](const ushort_t* as, int mh, int ks) {
    #pragma unroll
    for (int mi = 0; mi < MH; ++mi) {
      int row = wr * WM + (mh * MH + mi) * 16 + r16;
      int sl = (ks * 4 + quad) ^ (row & 7);
      af[mi] = *(const bf16x8*)&as[(row * 8 + sl) * 8];
    }
  };
  auto readB = [&](const ushort_t* bs, int ks, bf16x8* bfr) {
    #pragma unroll
    for (int ni = 0; ni < NIfr; ++ni) {
      int row = wc * WN + ni * 16 + r16;
      int sl = (ks * 4 + quad) ^ (row & 7);
      bfr[ni] = *(const bf16x8*)&bs[(row * 8 + sl) * 8];
    }
  };
  auto presync = [&]() {
    __builtin_amdgcn_sched_barrier(0);
    __builtin_amdgcn_s_barrier();
    asm volatile("s_waitcnt lgkmcnt(0)" ::: "memory");
    __builtin_amdgcn_sched_barrier(0);
  };
  auto mfmaC = [&](int mh, const bf16x8* bfr) {
    __builtin_amdgcn_s_setprio(1);
    #pragma unroll
    for (int mi = 0; mi < MH; ++mi)
      #pragma unroll
      for (int ni = 0; ni < NIfr; ++ni)
        acc[mh * MH + mi][ni] = __builtin_amdgcn_mfma_f32_16x16x32_bf16(
            af[mi], bfr[ni], acc[mh * MH + mi][ni], 0, 0, 0);
    __builtin_amdgcn_s_setprio(0);
    __builtin_amdgcn_sched_barrier(0);
  };

  // prologue: E.Bh0, E.Bh1, E.Ah0, E.Ah1, O.Bh0, O.Bh1
  stageB(0, 0); stageB(0, 1); stageA(0, 0); stageA(0, 1);
  stageB(1, 0); stageB(1, 1);
  waitv<2 * LB>();
  __builtin_amdgcn_s_barrier();

  const int NITER = K / 128;
  for (int it = 0; it < NITER; ++it) {
    const bool more = (it + 1 < NITER);
    // ===== K-tile E (buf 0) =====
    {
      const ushort_t* as = As;
      const ushort_t* bs = Bs;
      // P1
      readA(as, 0, 0); readB(bs, 0, b0);
      stageA(1, 0);
      presync(); mfmaC(0, b0);
      __builtin_amdgcn_s_barrier();
      // P2
      readB(bs, 1, b1); readA(as, 1, 0);
      stageA(1, 1);
      presync(); mfmaC(1, b0);
      __builtin_amdgcn_s_barrier();
      // P3
      readA(as, 0, 1);
      if (more) stageB(0, 0);
      presync(); mfmaC(0, b1);
      __builtin_amdgcn_s_barrier();
      // P4
      readA(as, 1, 1);
      if (more) stageB(0, 1);
      presync(); mfmaC(1, b1);
      if (more) waitv<2 * LB>(); else waitv<0>();
      __builtin_amdgcn_s_barrier();
    }
    // ===== K-tile O (buf 1) =====
    {
      const ushort_t* as = As + AST;
      const ushort_t* bs = Bs + BST;
      // P5
      readA(as, 0, 0); readB(bs, 0, b0);
      if (more) stageA(0, 0);
      presync(); mfmaC(0, b0);
      __builtin_amdgcn_s_barrier();
      // P6
      readB(bs, 1, b1); readA(as, 1, 0);
      if (more) stageA(0, 1);
      presync(); mfmaC(1, b0);
      __builtin_amdgcn_s_barrier();
      // P7
      readA(as, 0, 1);
      if (more) stageB(1, 0);
      presync(); mfmaC(0, b1);
      __builtin_amdgcn_s_barrier();
      // P8
      readA(as, 1, 1);
      if (more) stageB(1, 1);
      presync(); mfmaC(1, b1);
      if (more) waitv<2 * LB>();
      __builtin_amdgcn_s_barrier();
    }
  }

  // ---- epilogue: C/D layout col=lane&15, row=quad*4+reg ----
  float iv[MI][4];
  if constexpr (OUTMODE == OM_NORM) {
    #pragma unroll
    for (int mi = 0; mi < MI; ++mi)
      #pragma unroll
      for (int r = 0; r < 4; ++r)
        iv[mi][r] = invrs[rowBase + wr * WM + mi * 16 + quad * 4 + r];
  }

  float psum[MI][4];
  if constexpr (OUTMODE == OM_EXP) {
    #pragma unroll
    for (int mi = 0; mi < MI; ++mi)
      #pragma unroll
      for (int r = 0; r < 4; ++r) psum[mi][r] = 0.f;
  }

  #pragma unroll
  for (int mi = 0; mi < MI; ++mi)
    #pragma unroll
    for (int ni = 0; ni < NIfr; ++ni)
      #pragma unroll
      for (int r = 0; r < 4; ++r) {
        int grow = rowBase + wr * WM + mi * 16 + quad * 4 + r;
        int gcol = colBase + wc * WN + ni * 16 + r16;
        float a = acc[mi][ni][r];
        if constexpr (OUTMODE == OM_BF16) {
          ((ushort_t*)C)[(size_t)grow * ldc + gcol] = f2bf(a * scale);
        } else if constexpr (OUTMODE == OM_EXP) {
          float e = exp2f(a * scale);   // scale carries the log2(e) factor
          psum[mi][r] += e;
          ((ushort_t*)C)[(size_t)grow * ldc + gcol] = f2bf(e);
        } else {  // OM_NORM
          ((float*)C)[(size_t)grow * ldc + gcol] = a * iv[mi][r];
        }
      }

  if constexpr (OUTMODE == OM_EXP) {
    __syncthreads();                 // all LDS traffic done before reuse
    float* lds_rs = (float*)As;      // [4][256]
    #pragma unroll
    for (int mi = 0; mi < MI; ++mi)
      #pragma unroll
      for (int r = 0; r < 4; ++r) {
        float sv = psum[mi][r];
        sv += __shfl_xor(sv, 1, 64);
        sv += __shfl_xor(sv, 2, 64);
        sv += __shfl_xor(sv, 4, 64);
        sv += __shfl_xor(sv, 8, 64);
        if (r16 == 0)
          lds_rs[wc * 256 + wr * WM + mi * 16 + quad * 4 + r] = sv;
      }
    __syncthreads();
    if (t < 256)
      rsp[(size_t)nt * SEQ + rowBase + t] =
          lds_rs[t] + lds_rs[256 + t] + lds_rs[512 + t] + lds_rs[768 + t];
  }
}

extern "C" void kernel_launch(void* const* d_in, const int* in_sizes, int n_in,
                              void* d_out, int out_size, void* d_ws, size_t ws_size,
                              hipStream_t stream) {
  const float* x  = (const float*)d_in[0];
  const float* Wq = (const float*)d_in[1];
  const float* Wk = (const float*)d_in[2];
  const float* Wv = (const float*)d_in[3];
  float* out = (float*)d_out;

  char* p = (char*)d_ws;
  ushort_t* xb   = (ushort_t*)p; p += (size_t)SEQ * DIN * 2;        // 16 MB
  ushort_t* wqkb = (ushort_t*)p; p += (size_t)2 * DOUT * DIN * 2;   //  4 MB (Wq|Wk)
  ushort_t* wvb  = (ushort_t*)p; p += (size_t)DOUT * DIN * 2;       //  2 MB
  ushort_t* qkb  = (ushort_t*)p; p += (size_t)SEQ * 2 * DOUT * 2;   // 32 MB ([S][2048], q|k)
  ushort_t* vtb  = (ushort_t*)p; p += (size_t)DOUT * SEQ * 2;       // 16 MB (v^T)
  float*    rsp  = (float*)p;    p += (size_t)64 * SEQ * 4;         //  2 MB partial rowsums
  float*    irs  = (float*)p;    p += (size_t)SEQ * 4;              // 32 KB 1/rowsum
  ushort_t* Sb   = (ushort_t*)p; p += (size_t)SEQ * SEQ * 2;        // 128 MB

  // fp32 -> bf16 for all four tensors (one launch)
  cvt_all_kernel<<<8192 + 3 * 1024, 256, 0, stream>>>(x, Wq, Wk, Wv, xb, wqkb, wvb);

  dim3 blk(512);
  // [q|k] = x @ [Wq|Wk]^T : M=8192, N=2048, K=1024 -> 8x32 = 256 blocks
  gemm8p<OM_BF16, 0, 256, 256><<<dim3(2048 / 256, SEQ / 256), blk, 0, stream>>>(
      xb, wqkb, qkb, DIN, DIN, 2 * DOUT, DIN, 1.0f, nullptr, nullptr);

  // v^T = Wv @ x^T : M=1024, N=8192, K=1024 -> BM=128: 32x8 = 256 blocks
  gemm8p<OM_BF16, 0, 128, 256><<<dim3(SEQ / 256, DOUT / 128), blk, 0, stream>>>(
      wvb, xb, vtb, DIN, DIN, SEQ, DIN, 1.0f, nullptr, nullptr);

  // E = exp((q @ k^T)/32) via exp2, partial row sums -> rsp : 32x32 = 1024 blocks
  gemm8p<OM_EXP, 1, 256, 256><<<dim3(SEQ / 256, SEQ / 256), blk, 0, stream>>>(
      qkb, qkb + DOUT, Sb, 2 * DOUT, 2 * DOUT, SEQ, DIN,
      0.03125f * 1.44269504f, rsp, nullptr);

  // invrs[r] = 1 / sum_p rsp[p][r]  (32 partial tiles)
  rowsum_inv_kernel<<<SEQ / 256, 256, 0, stream>>>(rsp, irs);

  // out = (E @ v) * invrs : M=8192, N=1024, K=8192 -> BN=128: 8x32 = 256 blocks
  gemm8p<OM_NORM, 0, 256, 128><<<dim3(DOUT / 128, SEQ / 256), blk, 0, stream>>>(
      Sb, vtb, out, SEQ, SEQ, DOUT, SEQ, 1.0f, nullptr, irs);
}

// Round 5
// 456.615 us; speedup vs baseline: 1.2777x; 1.0398x over previous
//
#include <hip/hip_runtime.h>

typedef unsigned short ushort_t;
typedef __attribute__((ext_vector_type(8))) __bf16 bf16x8;
typedef __attribute__((ext_vector_type(4))) float f32x4;

#define SEQ 8192
#define DIN 1024
#define DOUT 1024

// epilogue output modes
#define OM_BF16 0
#define OM_EXP  2   // bf16 exp2(scale*acc) store + per-block partial row-sums -> rsp
#define OM_NORM 3   // f32 store of acc * invrs[row]

__device__ __forceinline__ ushort_t f2bf(float f) {
  union { float f; unsigned u; } c; c.f = f;
  unsigned u = c.u;
  return (ushort_t)((u + 0x7fffu + ((u >> 16) & 1u)) >> 16);  // RNE
}

__device__ __forceinline__ void async16(ushort_t* lds, const ushort_t* g) {
  __builtin_amdgcn_global_load_lds(
      (__attribute__((address_space(1))) void*)g,
      (__attribute__((address_space(3))) void*)lds, 16, 0, 0);
}

template <int N>
__device__ __forceinline__ void waitv() {
  asm volatile("s_waitcnt vmcnt(%0)" :: "n"(N) : "memory");
}

// ------- fused fp32 -> bf16 convert for x, Wq, Wk, Wv -------
__global__ __launch_bounds__(256) void cvt_all_kernel(
    const float* __restrict__ x, const float* __restrict__ wq,
    const float* __restrict__ wk, const float* __restrict__ wv,
    ushort_t* __restrict__ xb, ushort_t* __restrict__ wqkb,
    ushort_t* __restrict__ wvb) {
  int b = blockIdx.x;
  const float* src;
  ushort_t* dst;
  int idx;
  if (b < 8192) {
    src = x; dst = xb; idx = b * 256 + threadIdx.x;
  } else {
    int r = b - 8192;
    int w = r >> 10;
    idx = (r & 1023) * 256 + threadIdx.x;
    if (w == 0)      { src = wq; dst = wqkb; }
    else if (w == 1) { src = wk; dst = wqkb + DOUT * DIN; }
    else             { src = wv; dst = wvb; }
  }
  float4 f = ((const float4*)src)[idx];
  ushort4 o;
  o.x = f2bf(f.x); o.y = f2bf(f.y); o.z = f2bf(f.z); o.w = f2bf(f.w);
  ((ushort4*)dst)[idx] = o;
}

// ------- rowsum partials [32][SEQ] -> invrs[SEQ] = 1/sum -------
__global__ __launch_bounds__(256) void rowsum_inv_kernel(const float* __restrict__ rsp,
                                                         float* __restrict__ invrs) {
  int r = blockIdx.x * 256 + threadIdx.x;
  float s = 0.f;
  #pragma unroll
  for (int p2 = 0; p2 < 32; ++p2) s += rsp[p2 * SEQ + r];
  invrs[r] = 1.0f / s;
}

// ---------------- GEMM: C[M][N] = A[M][K] @ B[N][K]^T ----------------
// Round-5: same 8-region skeleton, stage plan and counted-vmcnt arithmetic as
// round 4 (proven correct), but regions now use INTRA-WAVE FRAGMENT PREFETCH:
// region r issues ds_reads for region r+1's fragments, then MFMAs fragments
// read in region r-1. No manual lgkmcnt / sched_barrier fences — plain-load
// ds_reads let the compiler insert fine-grained lgkmcnt (m97-verified), so the
// LDS port drains UNDER the MFMA cluster instead of alternating with it.
// Reads per tile: R1 {A-lo ks0, B ks0} (own, one lgkm stall/tile) + {A-hi ks0}
// (prefetch); R2 {A-lo ks1, B ks1}; R3 {A-hi ks1}; R4 none.
// Stage plan (unchanged): R1:O.Ah0 R2:O.Ah1 R3:E2.Bh0 R4:E2.Bh1
//                         R5:E2.Ah0 R6:E2.Ah1 R7:O2.Bh0 R8:O2.Bh1
// vmcnt(2*LB) at end of R4/R8 (before closing barrier) leaves exactly the two
// newest B-halves in flight; next tile's buffer is then block-wide landed
// (per-wave drain + barrier). Memory clobber only on the vmcnt asm and right
// after the two tile-close barriers (reads must not hoist above tile entry).
template <int OUTMODE, int SUPER, int BM, int BN>
__global__ __launch_bounds__(512, 2) void gemm8p(
    const ushort_t* __restrict__ A, const ushort_t* __restrict__ B,
    void* __restrict__ C, int lda, int ldb, int ldc, int K, float scale,
    float* __restrict__ rsp, const float* __restrict__ invrs) {
  constexpr int WM = BM / 2, WN = BN / 4;
  constexpr int MI = BM / 32, NIfr = BN / 64;
  constexpr int MH = MI / 2;
  constexpr int AST = BM * 64, BST = BN * 64;
  constexpr int AHALF = AST / 2, BHALF = BST / 2;
  constexpr int LA = BM / 128, LB = BN / 128;   // loads/thread per half
  __shared__ ushort_t As[2 * AST];
  __shared__ ushort_t Bs[2 * BST];

  const int t = threadIdx.x;
  const int lane = t & 63;
  const int wave = t >> 6;
  const int wr = wave >> 2, wc = wave & 3;
  const int quad = lane >> 4, r16 = lane & 15;

  const int gx = gridDim.x;
  const int nwg = gx * gridDim.y;
  const int bid = blockIdx.y * gx + blockIdx.x;
  int mt, nt;
  if (SUPER == 1) {
    // 32x32 grid only: XCD (x>>2, x&3) owns 16mt x 8nt, walked in 4x8 chunks
    int x = bid & 7, l = bid >> 3;
    mt = ((x >> 2) << 4) + ((l >> 5) << 2) + ((l >> 3) & 3);
    nt = ((x & 3) << 3) + (l & 7);
  } else {
    const int q8 = nwg >> 3;
    const int b2 = (bid & 7) * q8 + (bid >> 3);
    mt = b2 / gx;
    nt = b2 - mt * gx;
  }
  const int rowBase = mt * BM;
  const int colBase = nt * BN;

  // staging offsets (elements), one set per {operand, half}; +64 per use
  unsigned offA[2][LA], offB[2][LB];
  #pragma unroll
  for (int h = 0; h < 2; ++h) {
    #pragma unroll
    for (int i = 0; i < LA; ++i) {
      int c = t + i * 512, row = c >> 3, sl = c & 7;
      offA[h][i] = (unsigned)((rowBase + h * (BM / 2) + row) * lda +
                              ((sl ^ (row & 7)) << 3));
    }
    #pragma unroll
    for (int i = 0; i < LB; ++i) {
      int c = t + i * 512, row = c >> 3, sl = c & 7;
      offB[h][i] = (unsigned)((colBase + h * (BN / 2) + row) * ldb +
                              ((sl ^ (row & 7)) << 3));
    }
  }

  auto stageA = [&](int buf, int h) {
    #pragma unroll
    for (int i = 0; i < LA; ++i) {
      async16(&As[buf * AST + h * AHALF + (t + i * 512) * 8], A + offA[h][i]);
      offA[h][i] += 64;
    }
  };
  auto stageB = [&](int buf, int h) {
    #pragma unroll
    for (int i = 0; i < LB; ++i) {
      async16(&Bs[buf * BST + h * BHALF + (t + i * 512) * 8], B + offB[h][i]);
      offB[h][i] += 64;
    }
  };

  f32x4 acc[MI][NIfr] = {};
  bf16x8 aCur[MH], aNxt[MH], b0[NIfr], b1[NIfr];

  auto readA = [&](const ushort_t* as, int mh, int ks, bf16x8* dst) {
    #pragma unroll
    for (int mi = 0; mi < MH; ++mi) {
      int row = wr * WM + (mh * MH + mi) * 16 + r16;
      int sl = (ks * 4 + quad) ^ (row & 7);
      dst[mi] = *(const bf16x8*)&as[(row * 8 + sl) * 8];
    }
  };
  auto readB = [&](const ushort_t* bs, int ks, bf16x8* dst) {
    #pragma unroll
    for (int ni = 0; ni < NIfr; ++ni) {
      int row = wc * WN + ni * 16 + r16;
      int sl = (ks * 4 + quad) ^ (row & 7);
      dst[ni] = *(const bf16x8*)&bs[(row * 8 + sl) * 8];
    }
  };
  auto mfmaC = [&](int mh, const bf16x8* aset, const bf16x8* bfr) {
    __builtin_amdgcn_s_setprio(1);
    #pragma unroll
    for (int mi = 0; mi < MH; ++mi)
      #pragma unroll
      for (int ni = 0; ni < NIfr; ++ni)
        acc[mh * MH + mi][ni] = __builtin_amdgcn_mfma_f32_16x16x32_bf16(
            aset[mi], bfr[ni], acc[mh * MH + mi][ni], 0, 0, 0);
    __builtin_amdgcn_s_setprio(0);
  };

  // prologue: E.Bh0, E.Bh1, E.Ah0, E.Ah1, O.Bh0, O.Bh1
  stageB(0, 0); stageB(0, 1); stageA(0, 0); stageA(0, 1);
  stageB(1, 0); stageB(1, 1);
  waitv<2 * LB>();
  __builtin_amdgcn_s_barrier();
  asm volatile("" ::: "memory");

  const int NITER = K / 128;
  for (int it = 0; it < NITER; ++it) {
    const bool more = (it + 1 < NITER);
    // ===== K-tile E (buf 0) =====
    {
      const ushort_t* as = As;
      const ushort_t* bs = Bs;
      // R1: own reads (one lgkm stall/tile) + prefetch A-hi ks0
      readA(as, 0, 0, aCur); readB(bs, 0, b0);
      readA(as, 1, 0, aNxt);
      stageA(1, 0);
      mfmaC(0, aCur, b0);
      __builtin_amdgcn_s_barrier();
      // R2: prefetch {A-lo ks1, B ks1}; MFMA (hi, ks0)
      readA(as, 0, 1, aCur); readB(bs, 1, b1);
      stageA(1, 1);
      mfmaC(1, aNxt, b0);
      __builtin_amdgcn_s_barrier();
      // R3: prefetch {A-hi ks1}; MFMA (lo, ks1)
      readA(as, 1, 1, aNxt);
      if (more) stageB(0, 0);
      mfmaC(0, aCur, b1);
      __builtin_amdgcn_s_barrier();
      // R4: MFMA (hi, ks1); counted drain; tile close
      if (more) stageB(0, 1);
      mfmaC(1, aNxt, b1);
      if (more) waitv<2 * LB>(); else waitv<0>();
      __builtin_amdgcn_s_barrier();
      asm volatile("" ::: "memory");
    }
    // ===== K-tile O (buf 1) =====
    {
      const ushort_t* as = As + AST;
      const ushort_t* bs = Bs + BST;
      // R5
      readA(as, 0, 0, aCur); readB(bs, 0, b0);
      readA(as, 1, 0, aNxt);
      if (more) stageA(0, 0);
      mfmaC(0, aCur, b0);
      __builtin_amdgcn_s_barrier();
      // R6
      readA(as, 0, 1, aCur); readB(bs, 1, b1);
      if (more) stageA(0, 1);
      mfmaC(1, aNxt, b0);
      __builtin_amdgcn_s_barrier();
      // R7
      readA(as, 1, 1, aNxt);
      if (more) stageB(1, 0);
      mfmaC(0, aCur, b1);
      __builtin_amdgcn_s_barrier();
      // R8
      if (more) stageB(1, 1);
      mfmaC(1, aNxt, b1);
      if (more) waitv<2 * LB>();
      __builtin_amdgcn_s_barrier();
      asm volatile("" ::: "memory");
    }
  }

  // ---- epilogue: C/D layout col=lane&15, row=quad*4+reg ----
  float iv[MI][4];
  if constexpr (OUTMODE == OM_NORM) {
    #pragma unroll
    for (int mi = 0; mi < MI; ++mi)
      #pragma unroll
      for (int r = 0; r < 4; ++r)
        iv[mi][r] = invrs[rowBase + wr * WM + mi * 16 + quad * 4 + r];
  }

  float psum[MI][4];
  if constexpr (OUTMODE == OM_EXP) {
    #pragma unroll
    for (int mi = 0; mi < MI; ++mi)
      #pragma unroll
      for (int r = 0; r < 4; ++r) psum[mi][r] = 0.f;
  }

  #pragma unroll
  for (int mi = 0; mi < MI; ++mi)
    #pragma unroll
    for (int ni = 0; ni < NIfr; ++ni)
      #pragma unroll
      for (int r = 0; r < 4; ++r) {
        int grow = rowBase + wr * WM + mi * 16 + quad * 4 + r;
        int gcol = colBase + wc * WN + ni * 16 + r16;
        float a = acc[mi][ni][r];
        if constexpr (OUTMODE == OM_BF16) {
          ((ushort_t*)C)[(size_t)grow * ldc + gcol] = f2bf(a * scale);
        } else if constexpr (OUTMODE == OM_EXP) {
          float e = exp2f(a * scale);   // scale carries the log2(e) factor
          psum[mi][r] += e;
          ((ushort_t*)C)[(size_t)grow * ldc + gcol] = f2bf(e);
        } else {  // OM_NORM
          ((float*)C)[(size_t)grow * ldc + gcol] = a * iv[mi][r];
        }
      }

  if constexpr (OUTMODE == OM_EXP) {
    __syncthreads();                 // all LDS traffic done before reuse
    float* lds_rs = (float*)As;      // [4][256]
    #pragma unroll
    for (int mi = 0; mi < MI; ++mi)
      #pragma unroll
      for (int r = 0; r < 4; ++r) {
        float sv = psum[mi][r];
        sv += __shfl_xor(sv, 1, 64);
        sv += __shfl_xor(sv, 2, 64);
        sv += __shfl_xor(sv, 4, 64);
        sv += __shfl_xor(sv, 8, 64);
        if (r16 == 0)
          lds_rs[wc * 256 + wr * WM + mi * 16 + quad * 4 + r] = sv;
      }
    __syncthreads();
    if (t < 256)
      rsp[(size_t)nt * SEQ + rowBase + t] =
          lds_rs[t] + lds_rs[256 + t] + lds_rs[512 + t] + lds_rs[768 + t];
  }
}

extern "C" void kernel_launch(void* const* d_in, const int* in_sizes, int n_in,
                              void* d_out, int out_size, void* d_ws, size_t ws_size,
                              hipStream_t stream) {
  const float* x  = (const float*)d_in[0];
  const float* Wq = (const float*)d_in[1];
  const float* Wk = (const float*)d_in[2];
  const float* Wv = (const float*)d_in[3];
  float* out = (float*)d_out;

  char* p = (char*)d_ws;
  ushort_t* xb   = (ushort_t*)p; p += (size_t)SEQ * DIN * 2;        // 16 MB
  ushort_t* wqkb = (ushort_t*)p; p += (size_t)2 * DOUT * DIN * 2;   //  4 MB (Wq|Wk)
  ushort_t* wvb  = (ushort_t*)p; p += (size_t)DOUT * DIN * 2;       //  2 MB
  ushort_t* qkb  = (ushort_t*)p; p += (size_t)SEQ * 2 * DOUT * 2;   // 32 MB ([S][2048], q|k)
  ushort_t* vtb  = (ushort_t*)p; p += (size_t)DOUT * SEQ * 2;       // 16 MB (v^T)
  float*    rsp  = (float*)p;    p += (size_t)64 * SEQ * 4;         //  2 MB partial rowsums
  float*    irs  = (float*)p;    p += (size_t)SEQ * 4;              // 32 KB 1/rowsum
  ushort_t* Sb   = (ushort_t*)p; p += (size_t)SEQ * SEQ * 2;        // 128 MB

  // fp32 -> bf16 for all four tensors (one launch)
  cvt_all_kernel<<<8192 + 3 * 1024, 256, 0, stream>>>(x, Wq, Wk, Wv, xb, wqkb, wvb);

  dim3 blk(512);
  // [q|k] = x @ [Wq|Wk]^T : M=8192, N=2048, K=1024 -> 8x32 = 256 blocks
  gemm8p<OM_BF16, 0, 256, 256><<<dim3(2048 / 256, SEQ / 256), blk, 0, stream>>>(
      xb, wqkb, qkb, DIN, DIN, 2 * DOUT, DIN, 1.0f, nullptr, nullptr);

  // v^T = Wv @ x^T : M=1024, N=8192, K=1024 -> BM=128: 32x8 = 256 blocks
  gemm8p<OM_BF16, 0, 128, 256><<<dim3(SEQ / 256, DOUT / 128), blk, 0, stream>>>(
      wvb, xb, vtb, DIN, DIN, SEQ, DIN, 1.0f, nullptr, nullptr);

  // E = exp((q @ k^T)/32) via exp2, partial row sums -> rsp : 32x32 = 1024 blocks
  gemm8p<OM_EXP, 1, 256, 256><<<dim3(SEQ / 256, SEQ / 256), blk, 0, stream>>>(
      qkb, qkb + DOUT, Sb, 2 * DOUT, 2 * DOUT, SEQ, DIN,
      0.03125f * 1.44269504f, rsp, nullptr);

  // invrs[r] = 1 / sum_p rsp[p][r]  (32 partial tiles)
  rowsum_inv_kernel<<<SEQ / 256, 256, 0, stream>>>(rsp, irs);

  // out = (E @ v) * invrs : M=8192, N=1024, K=8192 -> BN=128: 8x32 = 256 blocks
  gemm8p<OM_NORM, 0, 256, 128><<<dim3(DOUT / 128, SEQ / 256), blk, 0, stream>>>(
      Sb, vtb, out, SEQ, SEQ, DOUT, SEQ, 1.0f, nullptr, irs);
}